// Round 1
// baseline (236.447 us; speedup 1.0000x reference)
//
#include <hip/hip_runtime.h>
#include <hip/hip_bf16.h>

// ---- problem constants ----
#define T_TOK 2048
#define HID   1024
#define FF    1024
#define NEXP  8
#define TOPK  2
#define NPAIR (T_TOK*TOPK)   // 4096

// ---- GEMM tiling ----
#define BM 128
#define BN 128
#define BK 32
#define MAX_MT 40            // max sum of ceil(n_e/128) over experts
#define MAXROWS (MAX_MT*BM)  // 5120

using bf16x8 = __attribute__((ext_vector_type(8))) __bf16;
using f32x4  = __attribute__((ext_vector_type(4))) float;

__device__ __forceinline__ unsigned short f2bf(float f) {
    unsigned int u = __float_as_uint(f);
    unsigned int r = (u + 0x7FFF + ((u >> 16) & 1)) >> 16;   // RNE
    return (unsigned short)r;
}
__device__ __forceinline__ float bf2f(unsigned short s) {
    return __uint_as_float(((unsigned int)s) << 16);
}

// ---------------- kernel 0: bucket (t,k) pairs by expert ----------------
__global__ void setup_kernel(const int* __restrict__ ids,
                             int* __restrict__ pair_pos,
                             int* __restrict__ meta) {
    __shared__ int cnt[NEXP], cnt2[NEXP], base[NEXP];
    int tid = threadIdx.x;
    if (tid < NEXP) { cnt[tid] = 0; cnt2[tid] = 0; }
    __syncthreads();
    for (int p = tid; p < NPAIR; p += 256) atomicAdd(&cnt[ids[p]], 1);
    __syncthreads();
    if (tid == 0) {
        int mt = 0;
        for (int e = 0; e < NEXP; e++) {
            meta[e] = mt;
            base[e] = mt * BM;
            mt += (cnt[e] + BM - 1) / BM;
        }
        meta[NEXP] = mt;
    }
    __syncthreads();
    for (int p = tid; p < NPAIR; p += 256) {
        int e = ids[p];
        int pos = base[e] + atomicAdd(&cnt2[e], 1);
        pair_pos[p] = pos;
    }
}

// ---------------- fp32 -> bf16 conversion (grid-stride, x4) ----------------
__global__ void cvt_bf16_kernel(const float* __restrict__ src,
                                unsigned short* __restrict__ dst, long n) {
    long i = ((long)blockIdx.x * blockDim.x + threadIdx.x) * 4;
    long stride = (long)gridDim.x * blockDim.x * 4;
    for (; i < n; i += stride) {
        float4 v = *(const float4*)(src + i);
        ushort4 o;
        o.x = f2bf(v.x); o.y = f2bf(v.y); o.z = f2bf(v.z); o.w = f2bf(v.w);
        *(ushort4*)(dst + i) = o;
    }
}

// ---------------- gather hidden rows into bucketed bf16 A ----------------
__global__ void gather_kernel(const float* __restrict__ hs,
                              const int* __restrict__ pair_pos,
                              unsigned short* __restrict__ A) {
    int p = blockIdx.x;          // 0..NPAIR-1
    int t = p >> 1;
    int pos = pair_pos[p];
    int c = threadIdx.x * 4;     // 256*4 = 1024 = HID
    float4 v = *(const float4*)(hs + (long)t * HID + c);
    ushort4 o;
    o.x = f2bf(v.x); o.y = f2bf(v.y); o.z = f2bf(v.z); o.w = f2bf(v.w);
    *(ushort4*)(A + (long)pos * HID + c) = o;
}

// ---------------- grouped GEMM: C[m,n] = sum_k A[m,k] * B_e[n,k] ----------------
// A: (rows x K) bf16 row-major. B: per-expert (Ntot x K) bf16 row-major.
// C: (rows x Ntot) bf16. m-tile bx belongs to expert e with meta[e] <= bx < meta[e+1].
__global__ __launch_bounds__(256)
void gemm_bt_moe(const unsigned short* __restrict__ A,
                 const unsigned short* __restrict__ B,
                 unsigned short* __restrict__ C,
                 const int* __restrict__ meta,
                 int K, int Ntot, long Bexp) {
    __shared__ unsigned short As[BM * BK];
    __shared__ unsigned short Bs[BN * BK];
    int bx = blockIdx.x, by = blockIdx.y;
    if (bx >= meta[NEXP]) return;
    int e = 0;
#pragma unroll
    for (int i = 1; i < NEXP; i++) if (bx >= meta[i]) e = i;

    long m0 = (long)bx * BM;
    long n0 = (long)by * BN;
    const unsigned short* Ab = A + m0 * K;
    const unsigned short* Bb = B + (long)e * Bexp + n0 * K;

    int tid = threadIdx.x, lane = tid & 63, wv = tid >> 6;
    const int qr8 = (lane >> 4) * 8;
    const int r = lane & 15;
    const int mw = (wv >> 1) * 64, nw = (wv & 1) * 64;

    f32x4 acc[4][4] = {};

    for (int k0 = 0; k0 < K; k0 += BK) {
        __syncthreads();
#pragma unroll
        for (int i = 0; i < 2; i++) {
            int chunk = i * 256 + tid;        // 512 chunks of 16B per tile
            int row = chunk >> 2, cc = chunk & 3;
            const unsigned short* ga = Ab + (long)row * K + k0 + cc * 8;
            const unsigned short* gb = Bb + (long)row * K + k0 + cc * 8;
            unsigned short* la = &As[(i * 256 + wv * 64) * 8];  // wave-uniform base
            unsigned short* lb = &Bs[(i * 256 + wv * 64) * 8];
            __builtin_amdgcn_global_load_lds((const __attribute__((address_space(1))) void*)(const void*)ga,
                                             (__attribute__((address_space(3))) void*)(void*)la, 16, 0, 0);
            __builtin_amdgcn_global_load_lds((const __attribute__((address_space(1))) void*)(const void*)gb,
                                             (__attribute__((address_space(3))) void*)(void*)lb, 16, 0, 0);
        }
        __syncthreads();

        bf16x8 a[4], b[4];
#pragma unroll
        for (int i = 0; i < 4; i++) {
            a[i] = *(const bf16x8*)&As[(mw + i * 16 + r) * BK + qr8];
            b[i] = *(const bf16x8*)&Bs[(nw + i * 16 + r) * BK + qr8];
        }
#pragma unroll
        for (int i = 0; i < 4; i++)
#pragma unroll
            for (int j = 0; j < 4; j++)
                acc[i][j] = __builtin_amdgcn_mfma_f32_16x16x32_bf16(a[i], b[j], acc[i][j], 0, 0, 0);
    }

    // epilogue: D row = quad*4+reg, col = lane&15  [m89-verified layout]
#pragma unroll
    for (int i = 0; i < 4; i++) {
        int rowb = mw + i * 16 + (lane >> 4) * 4;
#pragma unroll
        for (int j = 0; j < 4; j++) {
            int col = nw + j * 16 + r;
#pragma unroll
            for (int reg = 0; reg < 4; reg++) {
                C[(m0 + rowb + reg) * (long)Ntot + n0 + col] = f2bf(acc[i][j][reg]);
            }
        }
    }
}

// ---------------- silu(gate) * up ----------------
__global__ void silu_kernel(const unsigned short* __restrict__ gu,
                            unsigned short* __restrict__ act) {
    long idx = ((long)blockIdx.x * 256 + threadIdx.x) * 4;  // over MAXROWS*FF
    long row = idx >> 10;
    int f = (int)(idx & 1023);
    const unsigned short* gp = gu + row * (2 * FF) + f;
    ushort4 g = *(const ushort4*)gp;
    ushort4 u = *(const ushort4*)(gp + FF);
    ushort4 o;
    {
        float x = bf2f(g.x); o.x = f2bf(x / (1.f + __expf(-x)) * bf2f(u.x));
        float y = bf2f(g.y); o.y = f2bf(y / (1.f + __expf(-y)) * bf2f(u.y));
        float z = bf2f(g.z); o.z = f2bf(z / (1.f + __expf(-z)) * bf2f(u.z));
        float w = bf2f(g.w); o.w = f2bf(w / (1.f + __expf(-w)) * bf2f(u.w));
    }
    *(ushort4*)(act + row * FF + f) = o;
}

// ---------------- weighted combine: out[t,:] = w0*y[p0,:] + w1*y[p1,:] ----------------
__global__ void combine_kernel(const unsigned short* __restrict__ y,
                               const float* __restrict__ tw,
                               const int* __restrict__ pair_pos,
                               float* __restrict__ out) {
    int t = blockIdx.x;
    int c = threadIdx.x * 4;
    int p0 = pair_pos[t * 2], p1 = pair_pos[t * 2 + 1];
    float w0 = tw[t * 2], w1 = tw[t * 2 + 1];
    ushort4 a = *(const ushort4*)(y + (long)p0 * HID + c);
    ushort4 b = *(const ushort4*)(y + (long)p1 * HID + c);
    float4 o;
    o.x = w0 * bf2f(a.x) + w1 * bf2f(b.x);
    o.y = w0 * bf2f(a.y) + w1 * bf2f(b.y);
    o.z = w0 * bf2f(a.z) + w1 * bf2f(b.z);
    o.w = w0 * bf2f(a.w) + w1 * bf2f(b.w);
    *(float4*)(out + (long)t * HID + c) = o;
}

extern "C" void kernel_launch(void* const* d_in, const int* in_sizes, int n_in,
                              void* d_out, int out_size, void* d_ws, size_t ws_size,
                              hipStream_t stream) {
    const float* hs  = (const float*)d_in[0];
    const float* tw  = (const float*)d_in[1];
    const int*   ids = (const int*)d_in[2];
    const float* wgu = (const float*)d_in[3];
    const float* wdn = (const float*)d_in[4];
    float* out = (float*)d_out;

    char* ws = (char*)d_ws;
    size_t off = 0;
    auto alloc = [&](size_t bytes) -> void* {
        void* p = ws + off;
        off += (bytes + 255) & ~(size_t)255;
        return p;
    };
    unsigned short* wgu_b = (unsigned short*)alloc((size_t)NEXP * 2 * FF * HID * 2); // 32 MB
    unsigned short* wdn_b = (unsigned short*)alloc((size_t)NEXP * HID * FF * 2);     // 16 MB
    unsigned short* Abuf  = (unsigned short*)alloc((size_t)MAXROWS * HID * 2);       // 10 MB
    unsigned short* gu    = (unsigned short*)alloc((size_t)MAXROWS * 2 * FF * 2);    // 20 MB
    unsigned short* act   = (unsigned short*)alloc((size_t)MAXROWS * FF * 2);        // 10 MB
    unsigned short* ybuf  = (unsigned short*)alloc((size_t)MAXROWS * HID * 2);       // 10 MB
    int* pair_pos = (int*)alloc(NPAIR * 4);
    int* meta     = (int*)alloc(64);

    // zero-fill A so padded segment rows contribute zeros (partial M-tiles safe)
    hipMemsetAsync(Abuf, 0, (size_t)MAXROWS * HID * 2, stream);

    setup_kernel<<<1, 256, 0, stream>>>(ids, pair_pos, meta);
    cvt_bf16_kernel<<<4096, 256, 0, stream>>>(wgu, wgu_b, (long)NEXP * 2 * FF * HID);
    cvt_bf16_kernel<<<2048, 256, 0, stream>>>(wdn, wdn_b, (long)NEXP * HID * FF);
    gather_kernel<<<NPAIR, 256, 0, stream>>>(hs, pair_pos, Abuf);

    gemm_bt_moe<<<dim3(MAX_MT, (2 * FF) / BN), 256, 0, stream>>>(
        Abuf, wgu_b, gu, meta, HID, 2 * FF, (long)(2 * FF) * HID);
    silu_kernel<<<MAXROWS, 256, 0, stream>>>(gu, act);
    gemm_bt_moe<<<dim3(MAX_MT, HID / BN), 256, 0, stream>>>(
        act, wdn_b, ybuf, meta, FF, HID, (long)HID * FF);
    combine_kernel<<<T_TOK, 256, 0, stream>>>(ybuf, tw, pair_pos, out);
}